// Round 5
// baseline (1035.366 us; speedup 1.0000x reference)
//
#include <hip/hip_runtime.h>

#define N_DRUG 50000
#define F_DRUG 256
#define E_DRUG 1000000
#define N_DIS  20000
#define F_DIS  128
#define E_DIS  640000
#define NHID   64

#define NBKT 512   // padded bucket-array size (actual: 391 drug, 157 dis @ shift 7)
#define ROWS 128   // nodes per bucket

typedef __bf16 bf16x8 __attribute__((ext_vector_type(8)));
typedef float  f32x4  __attribute__((ext_vector_type(4)));

__device__ inline float bf2f(unsigned short u) {
    union { unsigned int i; float f; } c;
    c.i = ((unsigned int)u) << 16;
    return c.f;
}

// ---------------- prepack W -> bf16, MFMA-B-fragment layout ----------------
__global__ void prepack_kernel(const float* __restrict__ W1, __bf16* __restrict__ Wp1, int n1,
                               const float* __restrict__ W2, __bf16* __restrict__ Wp2, int n2) {
    int i = blockIdx.x * blockDim.x + threadIdx.x;
    const float* W; __bf16* Wp; int idx;
    if (i < n1) { W = W1; Wp = Wp1; idx = i; }
    else if (i < n1 + n2) { W = W2; Wp = Wp2; idx = i - n1; }
    else return;
    int k = idx >> 6, col = idx & 63;
    Wp[((size_t)(k >> 3) * 64 + col) * 8 + (k & 7)] = (__bf16)W[idx];
}

// ---------------- MFMA GEMM: h[M,64](bf16) = bf16(x[M,K]) @ bf16(W[K,64]) ----------------
template <int K>
__global__ void __launch_bounds__(256)
mfma_gemm_kernel(const float* __restrict__ x, const __bf16* __restrict__ Wp,
                 __bf16* __restrict__ h, int M) {
    __shared__ __bf16 Wlds[K * 64];
    {
        const int4* src = (const int4*)Wp;
        int4* dst = (int4*)Wlds;
        const int nchunk = K * 64 * 2 / 16;
        for (int i = threadIdx.x; i < nchunk; i += 256) dst[i] = src[i];
    }
    __syncthreads();

    const int wid = threadIdx.x >> 6, lane = threadIdx.x & 63;
    const int l15 = lane & 15, lhi = lane >> 4;
    const int r0 = blockIdx.x * 128 + wid * 32;
    if (r0 >= M) return;

    f32x4 acc[2][4];
#pragma unroll
    for (int m = 0; m < 2; ++m)
#pragma unroll
        for (int c = 0; c < 4; ++c) acc[m][c] = {0.f, 0.f, 0.f, 0.f};

    int rowA0 = r0 + l15;
    int rowA1 = r0 + 16 + l15;
    int cr0 = rowA0 < M ? rowA0 : M - 1;
    int cr1 = rowA1 < M ? rowA1 : M - 1;
    const float* pA0 = x + (size_t)cr0 * K + lhi * 8;
    const float* pA1 = x + (size_t)cr1 * K + lhi * 8;
    const bf16x8* Wv = (const bf16x8*)Wlds;

    for (int kk = 0; kk < K; kk += 32) {
        float4 a0l = *(const float4*)(pA0 + kk);
        float4 a0h = *(const float4*)(pA0 + kk + 4);
        float4 a1l = *(const float4*)(pA1 + kk);
        float4 a1h = *(const float4*)(pA1 + kk + 4);
        bf16x8 af0, af1;
        af0[0] = (__bf16)a0l.x; af0[1] = (__bf16)a0l.y;
        af0[2] = (__bf16)a0l.z; af0[3] = (__bf16)a0l.w;
        af0[4] = (__bf16)a0h.x; af0[5] = (__bf16)a0h.y;
        af0[6] = (__bf16)a0h.z; af0[7] = (__bf16)a0h.w;
        af1[0] = (__bf16)a1l.x; af1[1] = (__bf16)a1l.y;
        af1[2] = (__bf16)a1l.z; af1[3] = (__bf16)a1l.w;
        af1[4] = (__bf16)a1h.x; af1[5] = (__bf16)a1h.y;
        af1[6] = (__bf16)a1h.z; af1[7] = (__bf16)a1h.w;
        const int kblk = (kk >> 3) + lhi;
#pragma unroll
        for (int c = 0; c < 4; ++c) {
            bf16x8 bf = Wv[kblk * 64 + c * 16 + l15];
            acc[0][c] = __builtin_amdgcn_mfma_f32_16x16x32_bf16(af0, bf, acc[0][c], 0, 0, 0);
            acc[1][c] = __builtin_amdgcn_mfma_f32_16x16x32_bf16(af1, bf, acc[1][c], 0, 0, 0);
        }
    }

#pragma unroll
    for (int m = 0; m < 2; ++m) {
        int rbase = r0 + m * 16 + lhi * 4;
#pragma unroll
        for (int c = 0; c < 4; ++c) {
            int col = c * 16 + l15;
#pragma unroll
            for (int r = 0; r < 4; ++r) {
                int row = rbase + r;
                if (row < M) h[(size_t)row * 64 + col] = (__bf16)acc[m][c][r];
            }
        }
    }
}

// ---------------- bucket machinery ----------------
__global__ void zero_bcnt_kernel(int* __restrict__ a, int* __restrict__ b) {
    int i = threadIdx.x;
    for (; i < NBKT; i += 256) { a[i] = 0; b[i] = 0; }
}

__global__ void __launch_bounds__(256)
bucket_hist_kernel(const int* __restrict__ ei, int E, int shift, int* __restrict__ gcnt) {
    __shared__ int h[NBKT];
    for (int i = threadIdx.x; i < NBKT; i += 256) h[i] = 0;
    __syncthreads();
    int stride = gridDim.x * 256;
    for (int i = blockIdx.x * 256 + threadIdx.x; i < E; i += stride)
        atomicAdd(&h[ei[E + i] >> shift], 1);
    __syncthreads();
    for (int i = threadIdx.x; i < NBKT; i += 256)
        if (h[i]) atomicAdd(&gcnt[i], h[i]);
}

__global__ void scan_buckets_kernel(const int* __restrict__ c1, int* __restrict__ s1, int* __restrict__ cur1,
                                    const int* __restrict__ c2, int* __restrict__ s2, int* __restrict__ cur2) {
    const int* c; int* s; int* cur;
    if (blockIdx.x == 0) { c = c1; s = s1; cur = cur1; }
    else                 { c = c2; s = s2; cur = cur2; }
    int lane = threadIdx.x;   // 64 threads
    int run = 0;
    for (int ch = 0; ch < NBKT / 64; ++ch) {
        int v = c[ch * 64 + lane];
        int incl = v;
#pragma unroll
        for (int off = 1; off < 64; off <<= 1) {
            int t = __shfl_up(incl, off);
            if (lane >= off) incl += t;
        }
        int ex = run + incl - v;
        s[ch * 64 + lane] = ex;
        cur[ch * 64 + lane] = ex;
        run += __shfl(incl, 63);
    }
    if (lane == 0) s[NBKT] = run;
}

// Bin edges by bucket: local LDS reorder -> coalesced run writes.
__global__ void __launch_bounds__(256)
bin_kernel(const int* __restrict__ ei, int E, int shift,
           int* __restrict__ gcur, int2* __restrict__ binned) {
    __shared__ int hist[NBKT];
    __shared__ int excl[NBKT];
    __shared__ int gbase[NBKT];
    __shared__ int2 buf[4096];

    const int tid = threadIdx.x;
    const int base = blockIdx.x * 4096;
    const int total = min(4096, E - base);

    for (int i = tid; i < NBKT; i += 256) hist[i] = 0;
    __syncthreads();

    int2 my[16];
    int mybkt[16];
    int myloc[16];
#pragma unroll
    for (int j = 0; j < 16; ++j) {
        int e = base + j * 256 + tid;
        if (e < E) {
            int s = ei[e];
            int d = ei[E + e];
            my[j] = make_int2(s, d);
            mybkt[j] = d >> shift;
            myloc[j] = atomicAdd(&hist[mybkt[j]], 1);
        } else {
            mybkt[j] = -1;
        }
    }
    __syncthreads();

    if (tid < 64) {
        int run = 0;
        for (int ch = 0; ch < NBKT / 64; ++ch) {
            int v = hist[ch * 64 + tid];
            int incl = v;
#pragma unroll
            for (int off = 1; off < 64; off <<= 1) {
                int t = __shfl_up(incl, off);
                if (tid >= off) incl += t;
            }
            excl[ch * 64 + tid] = run + incl - v;
            run += __shfl(incl, 63);
        }
    }
    __syncthreads();

    for (int i = tid; i < NBKT; i += 256) {
        int cnt = hist[i];
        if (cnt) gbase[i] = atomicAdd(&gcur[i], cnt);
    }
    __syncthreads();

#pragma unroll
    for (int j = 0; j < 16; ++j)
        if (mybkt[j] >= 0) buf[excl[mybkt[j]] + myloc[j]] = my[j];
    __syncthreads();

    for (int s = tid; s < total; s += 256) {
        int2 p = buf[s];
        int b = p.y >> shift;
        binned[gbase[b] + (s - excl[b])] = p;
    }
}

// ---------------- combined bucket aggregation (both graphs, one launch) ----------------
// 1024 threads = 16 waves per block; one block per bucket of 128 nodes.
// Lanes 0-7 load 8 edge pairs; shfl-broadcast; all indices compile-time (no scratch).
__global__ void __launch_bounds__(1024)
agg2_kernel(const int2* __restrict__ bin1, const int* __restrict__ bs1,
            const unsigned short* __restrict__ h1, const float* __restrict__ bias1,
            float* __restrict__ out1, int N1, int NB1,
            const int2* __restrict__ bin2, const int* __restrict__ bs2,
            const unsigned short* __restrict__ h2, const float* __restrict__ bias2,
            float* __restrict__ out2, int N2) {
    __shared__ float tile[ROWS * 64];
    const int lane = threadIdx.x & 63;
    const int w = threadIdx.x >> 6;      // 0..15

    const int2* binned; const int* bstart; const unsigned short* hbf;
    const float* bias; float* out; int N; int b;
    if ((int)blockIdx.x < NB1) {
        binned = bin1; bstart = bs1; hbf = h1; bias = bias1; out = out1; N = N1; b = blockIdx.x;
    } else {
        binned = bin2; bstart = bs2; hbf = h2; bias = bias2; out = out2; N = N2; b = blockIdx.x - NB1;
    }

    for (int i = threadIdx.x; i < ROWS * 16; i += 1024)
        ((float4*)tile)[i] = make_float4(0.f, 0.f, 0.f, 0.f);
    __syncthreads();

    const int s = bstart[b], e = bstart[b + 1];
    const int per = (e - s + 15) >> 4;
    const int ws = s + w * per;
    const int we = min(ws + per, e);

    int e0 = ws;
    for (; e0 + 8 <= we; e0 += 8) {
        int2 pv = binned[e0 + (lane & 7)];
        int srcn[8], loc[8]; float v[8];
#pragma unroll
        for (int k = 0; k < 8; ++k) {
            srcn[k] = __shfl(pv.x, k);
            loc[k]  = __shfl(pv.y, k) & (ROWS - 1);
        }
#pragma unroll
        for (int k = 0; k < 8; ++k)
            v[k] = bf2f(hbf[(size_t)srcn[k] * 64 + lane]);
#pragma unroll
        for (int k = 0; k < 8; ++k)
            atomicAdd(&tile[loc[k] * 64 + lane], v[k]);
    }
    if (e0 < we) {
        int idx = e0 + (lane & 7);
        if (idx >= we) idx = we - 1;     // clamp; bound is wave-uniform
        int2 pv = binned[idx];
#pragma unroll
        for (int k = 0; k < 8; ++k) {
            if (e0 + k < we) {           // wave-uniform predicate
                int sn = __shfl(pv.x, k);
                int lc = __shfl(pv.y, k) & (ROWS - 1);
                atomicAdd(&tile[lc * 64 + lane], bf2f(hbf[(size_t)sn * 64 + lane]));
            }
        }
    }
    __syncthreads();

    const int rowbase = b * ROWS;
    for (int i = threadIdx.x; i < ROWS * 64; i += 1024) {
        int r = i >> 6, col = i & 63;
        int row = rowbase + r;
        if (row < N) out[(size_t)row * 64 + col] = tile[i] + bias[col];
    }
}

extern "C" void kernel_launch(void* const* d_in, const int* in_sizes, int n_in,
                              void* d_out, int out_size, void* d_ws, size_t ws_size,
                              hipStream_t stream) {
    const float* drug_x = (const float*)d_in[0];
    const float* dis_x  = (const float*)d_in[1];
    const float* W1     = (const float*)d_in[2];
    const float* b1     = (const float*)d_in[3];
    const float* W2     = (const float*)d_in[4];
    const float* b2     = (const float*)d_in[5];
    const int*   ei1    = (const int*)d_in[6];
    const int*   ei2    = (const int*)d_in[7];
    float* out = (float*)d_out;

    // workspace layout (all chunks 16B-aligned)
    char* p = (char*)d_ws;
    __bf16* h1 = (__bf16*)p;   p += (size_t)N_DRUG * NHID * 2;
    __bf16* h2 = (__bf16*)p;   p += (size_t)N_DIS  * NHID * 2;
    int2* bin1 = (int2*)p;     p += (size_t)E_DRUG * 8;
    int2* bin2 = (int2*)p;     p += (size_t)E_DIS  * 8;
    int* bcnt1   = (int*)p;    p += NBKT * 4;
    int* bstart1 = (int*)p;    p += (NBKT + 4) * 4;
    int* bcur1   = (int*)p;    p += NBKT * 4;
    int* bcnt2   = (int*)p;    p += NBKT * 4;
    int* bstart2 = (int*)p;    p += (NBKT + 4) * 4;
    int* bcur2   = (int*)p;    p += NBKT * 4;
    __bf16* Wp1 = (__bf16*)p;  p += (size_t)F_DRUG * NHID * 2;
    __bf16* Wp2 = (__bf16*)p;

    const int SH = 7;                              // bucket = dst >> 7, ROWS = 128
    const int B1n = (N_DRUG + ROWS - 1) / ROWS;    // 391
    const int B2n = (N_DIS  + ROWS - 1) / ROWS;    // 157

    // 1) zero bucket counters
    zero_bcnt_kernel<<<1, 256, 0, stream>>>(bcnt1, bcnt2);
    // 2) bucket histograms
    bucket_hist_kernel<<<1024, 256, 0, stream>>>(ei1, E_DRUG, SH, bcnt1);
    bucket_hist_kernel<<<640,  256, 0, stream>>>(ei2, E_DIS,  SH, bcnt2);
    // 3) bucket scans (starts + cursors)
    scan_buckets_kernel<<<2, 64, 0, stream>>>(bcnt1, bstart1, bcur1, bcnt2, bstart2, bcur2);
    // 4) bin edges (coalesced run writes)
    bin_kernel<<<(E_DRUG + 4095) / 4096, 256, 0, stream>>>(ei1, E_DRUG, SH, bcur1, bin1);
    bin_kernel<<<(E_DIS  + 4095) / 4096, 256, 0, stream>>>(ei2, E_DIS,  SH, bcur2, bin2);
    // 5) prepack W + MFMA GEMMs (h in bf16)
    {
        int n1 = F_DRUG * NHID, n2 = F_DIS * NHID;
        prepack_kernel<<<(n1 + n2 + 255) / 256, 256, 0, stream>>>(W1, Wp1, n1, W2, Wp2, n2);
    }
    mfma_gemm_kernel<F_DRUG><<<(N_DRUG + 127) / 128, 256, 0, stream>>>(drug_x, Wp1, h1, N_DRUG);
    mfma_gemm_kernel<F_DIS ><<<(N_DIS  + 127) / 128, 256, 0, stream>>>(dis_x,  Wp2, h2, N_DIS);
    // 6) combined bucket aggregation (+bias), one launch for both graphs
    agg2_kernel<<<B1n + B2n, 1024, 0, stream>>>(
        bin1, bstart1, (const unsigned short*)h1, b1, out, N_DRUG, B1n,
        bin2, bstart2, (const unsigned short*)h2, b2, out + (size_t)N_DRUG * NHID, N_DIS);
}

// Round 6
// 160.427 us; speedup vs baseline: 6.4538x; 6.4538x over previous
//
#include <hip/hip_runtime.h>

#define N_DRUG 50000
#define F_DRUG 256
#define E_DRUG 1000000
#define N_DIS  20000
#define F_DIS  128
#define E_DIS  640000
#define NHID   64

#define NBKT 512   // padded bucket-count array (actual: 391 drug @sh7, 313 dis @sh6)
#define CAP  5120  // per-bucket edge capacity in LDS (mean 2558/2044, +29 sigma safe)

typedef __bf16 bf16x8 __attribute__((ext_vector_type(8)));
typedef float  f32x4  __attribute__((ext_vector_type(4)));

__device__ inline float bf2f(unsigned short u) {
    union { unsigned int i; float f; } c;
    c.i = ((unsigned int)u) << 16;
    return c.f;
}

// ---------------- prepack W -> bf16, MFMA-B-fragment layout ----------------
__global__ void prepack_kernel(const float* __restrict__ W1, __bf16* __restrict__ Wp1, int n1,
                               const float* __restrict__ W2, __bf16* __restrict__ Wp2, int n2) {
    int i = blockIdx.x * blockDim.x + threadIdx.x;
    const float* W; __bf16* Wp; int idx;
    if (i < n1) { W = W1; Wp = Wp1; idx = i; }
    else if (i < n1 + n2) { W = W2; Wp = Wp2; idx = i - n1; }
    else return;
    int k = idx >> 6, col = idx & 63;
    Wp[((size_t)(k >> 3) * 64 + col) * 8 + (k & 7)] = (__bf16)W[idx];
}

// ---------------- MFMA GEMM: h[M,64](bf16) = bf16(x[M,K]) @ bf16(W[K,64]) ----------------
template <int K>
__global__ void __launch_bounds__(256)
mfma_gemm_kernel(const float* __restrict__ x, const __bf16* __restrict__ Wp,
                 __bf16* __restrict__ h, int M) {
    __shared__ __bf16 Wlds[K * 64];
    {
        const int4* src = (const int4*)Wp;
        int4* dst = (int4*)Wlds;
        const int nchunk = K * 64 * 2 / 16;
        for (int i = threadIdx.x; i < nchunk; i += 256) dst[i] = src[i];
    }
    __syncthreads();

    const int wid = threadIdx.x >> 6, lane = threadIdx.x & 63;
    const int l15 = lane & 15, lhi = lane >> 4;
    const int r0 = blockIdx.x * 128 + wid * 32;
    if (r0 >= M) return;

    f32x4 acc[2][4];
#pragma unroll
    for (int m = 0; m < 2; ++m)
#pragma unroll
        for (int c = 0; c < 4; ++c) acc[m][c] = {0.f, 0.f, 0.f, 0.f};

    int rowA0 = r0 + l15;
    int rowA1 = r0 + 16 + l15;
    int cr0 = rowA0 < M ? rowA0 : M - 1;
    int cr1 = rowA1 < M ? rowA1 : M - 1;
    const float* pA0 = x + (size_t)cr0 * K + lhi * 8;
    const float* pA1 = x + (size_t)cr1 * K + lhi * 8;
    const bf16x8* Wv = (const bf16x8*)Wlds;

    for (int kk = 0; kk < K; kk += 32) {
        float4 a0l = *(const float4*)(pA0 + kk);
        float4 a0h = *(const float4*)(pA0 + kk + 4);
        float4 a1l = *(const float4*)(pA1 + kk);
        float4 a1h = *(const float4*)(pA1 + kk + 4);
        bf16x8 af0, af1;
        af0[0] = (__bf16)a0l.x; af0[1] = (__bf16)a0l.y;
        af0[2] = (__bf16)a0l.z; af0[3] = (__bf16)a0l.w;
        af0[4] = (__bf16)a0h.x; af0[5] = (__bf16)a0h.y;
        af0[6] = (__bf16)a0h.z; af0[7] = (__bf16)a0h.w;
        af1[0] = (__bf16)a1l.x; af1[1] = (__bf16)a1l.y;
        af1[2] = (__bf16)a1l.z; af1[3] = (__bf16)a1l.w;
        af1[4] = (__bf16)a1h.x; af1[5] = (__bf16)a1h.y;
        af1[6] = (__bf16)a1h.z; af1[7] = (__bf16)a1h.w;
        const int kblk = (kk >> 3) + lhi;
#pragma unroll
        for (int c = 0; c < 4; ++c) {
            bf16x8 bf = Wv[kblk * 64 + c * 16 + l15];
            acc[0][c] = __builtin_amdgcn_mfma_f32_16x16x32_bf16(af0, bf, acc[0][c], 0, 0, 0);
            acc[1][c] = __builtin_amdgcn_mfma_f32_16x16x32_bf16(af1, bf, acc[1][c], 0, 0, 0);
        }
    }

#pragma unroll
    for (int m = 0; m < 2; ++m) {
        int rbase = r0 + m * 16 + lhi * 4;
#pragma unroll
        for (int c = 0; c < 4; ++c) {
            int col = c * 16 + l15;
#pragma unroll
            for (int r = 0; r < 4; ++r) {
                int row = rbase + r;
                if (row < M) h[(size_t)row * 64 + col] = (__bf16)acc[m][c][r];
            }
        }
    }
}

// ---------------- bucket machinery ----------------
__global__ void zero_bcnt_kernel(int* __restrict__ a, int* __restrict__ b) {
    int i = threadIdx.x;
    for (; i < NBKT; i += 256) { a[i] = 0; b[i] = 0; }
}

__global__ void __launch_bounds__(256)
bucket_hist_kernel(const int* __restrict__ ei, int E, int shift, int* __restrict__ gcnt) {
    __shared__ int h[NBKT];
    for (int i = threadIdx.x; i < NBKT; i += 256) h[i] = 0;
    __syncthreads();
    int stride = gridDim.x * 256;
    for (int i = blockIdx.x * 256 + threadIdx.x; i < E; i += stride)
        atomicAdd(&h[ei[E + i] >> shift], 1);
    __syncthreads();
    for (int i = threadIdx.x; i < NBKT; i += 256)
        if (h[i]) atomicAdd(&gcnt[i], h[i]);
}

__global__ void scan_buckets_kernel(const int* __restrict__ c1, int* __restrict__ s1, int* __restrict__ cur1,
                                    const int* __restrict__ c2, int* __restrict__ s2, int* __restrict__ cur2) {
    const int* c; int* s; int* cur;
    if (blockIdx.x == 0) { c = c1; s = s1; cur = cur1; }
    else                 { c = c2; s = s2; cur = cur2; }
    int lane = threadIdx.x;   // 64 threads
    int run = 0;
    for (int ch = 0; ch < NBKT / 64; ++ch) {
        int v = c[ch * 64 + lane];
        int incl = v;
#pragma unroll
        for (int off = 1; off < 64; off <<= 1) {
            int t = __shfl_up(incl, off);
            if (lane >= off) incl += t;
        }
        int ex = run + incl - v;
        s[ch * 64 + lane] = ex;
        cur[ch * 64 + lane] = ex;
        run += __shfl(incl, 63);
    }
    if (lane == 0) s[NBKT] = run;
}

// Bin edges by bucket: local LDS reorder -> coalesced run writes. (proven in R3)
__global__ void __launch_bounds__(256)
bin_kernel(const int* __restrict__ ei, int E, int shift,
           int* __restrict__ gcur, int2* __restrict__ binned) {
    __shared__ int hist[NBKT];
    __shared__ int excl[NBKT];
    __shared__ int gbase[NBKT];
    __shared__ int2 buf[4096];

    const int tid = threadIdx.x;
    const int base = blockIdx.x * 4096;
    const int total = min(4096, E - base);

    for (int i = tid; i < NBKT; i += 256) hist[i] = 0;
    __syncthreads();

    int2 my[16];
    int mybkt[16];
    int myloc[16];
#pragma unroll
    for (int j = 0; j < 16; ++j) {
        int e = base + j * 256 + tid;
        if (e < E) {
            int s = ei[e];
            int d = ei[E + e];
            my[j] = make_int2(s, d);
            mybkt[j] = d >> shift;
            myloc[j] = atomicAdd(&hist[mybkt[j]], 1);
        } else {
            mybkt[j] = -1;
        }
    }
    __syncthreads();

    if (tid < 64) {
        int run = 0;
        for (int ch = 0; ch < NBKT / 64; ++ch) {
            int v = hist[ch * 64 + tid];
            int incl = v;
#pragma unroll
            for (int off = 1; off < 64; off <<= 1) {
                int t = __shfl_up(incl, off);
                if (tid >= off) incl += t;
            }
            excl[ch * 64 + tid] = run + incl - v;
            run += __shfl(incl, 63);
        }
    }
    __syncthreads();

    for (int i = tid; i < NBKT; i += 256) {
        int cnt = hist[i];
        if (cnt) gbase[i] = atomicAdd(&gcur[i], cnt);
    }
    __syncthreads();

#pragma unroll
    for (int j = 0; j < 16; ++j)
        if (mybkt[j] >= 0) buf[excl[mybkt[j]] + myloc[j]] = my[j];
    __syncthreads();

    for (int s = tid; s < total; s += 256) {
        int2 p = buf[s];
        int b = p.y >> shift;
        binned[gbase[b] + (s - excl[b])] = p;
    }
}

// ---------------- fused per-bucket sort + register-accumulation gather ----------------
// One block (512 thr = 8 waves) per bucket. Build per-node CSR in LDS (int atomics),
// then wave-per-node gather with 4 independent fp32 accumulators. No LDS float atomics.
__global__ void __launch_bounds__(512)
sortgather_kernel(const int2* __restrict__ bin1, const int* __restrict__ bs1,
                  const unsigned short* __restrict__ h1, const float* __restrict__ bias1,
                  float* __restrict__ out1, int N1, int NB1, int rows1,
                  const int2* __restrict__ bin2, const int* __restrict__ bs2,
                  const unsigned short* __restrict__ h2, const float* __restrict__ bias2,
                  float* __restrict__ out2, int N2, int rows2) {
    __shared__ int hist[128];
    __shared__ int nstart[129];
    __shared__ int cur[128];
    __shared__ int srcbuf[CAP];

    const int2* binned; const int* bstart; const unsigned short* hbf;
    const float* bias; float* out; int N, b, rows;
    if ((int)blockIdx.x < NB1) {
        binned = bin1; bstart = bs1; hbf = h1; bias = bias1; out = out1;
        N = N1; b = blockIdx.x; rows = rows1;
    } else {
        binned = bin2; bstart = bs2; hbf = h2; bias = bias2; out = out2;
        N = N2; b = blockIdx.x - NB1; rows = rows2;
    }

    const int tid = threadIdx.x;
    const int lane = tid & 63, w = tid >> 6;
    const int mask = rows - 1;

    for (int i = tid; i < rows; i += 512) hist[i] = 0;
    __syncthreads();

    const int s = bstart[b];
    int cnt = bstart[b + 1] - s;
    if (cnt > CAP) cnt = CAP;   // statistically unreachable; memory-safety only

    // pass 1: per-node histogram (LDS int atomics)
    for (int i = tid; i < cnt; i += 512)
        atomicAdd(&hist[binned[s + i].y & mask], 1);
    __syncthreads();

    // exclusive scan by wave 0
    if (tid < 64) {
        int run = 0;
        for (int ch = 0; ch * 64 < rows; ++ch) {
            int v = hist[ch * 64 + tid];
            int incl = v;
#pragma unroll
            for (int off = 1; off < 64; off <<= 1) {
                int t = __shfl_up(incl, off);
                if (tid >= off) incl += t;
            }
            nstart[ch * 64 + tid] = run + incl - v;
            run += __shfl(incl, 63);
        }
        if (tid == 0) nstart[rows] = run;
    }
    __syncthreads();
    for (int i = tid; i < rows; i += 512) cur[i] = nstart[i];
    __syncthreads();

    // pass 2: scatter src ids into node-sorted LDS order
    for (int i = tid; i < cnt; i += 512) {
        int2 p = binned[s + i];
        int pos = atomicAdd(&cur[p.y & mask], 1);
        srcbuf[pos] = p.x;
    }
    __syncthreads();

    // gather: wave per node, 4 independent accumulators
    const float bl = bias[lane];
    const int rowbase = b * rows;
    for (int n = w; n < rows; n += 8) {
        int row = rowbase + n;
        if (row >= N) break;               // wave-uniform
        int j = nstart[n], jend = nstart[n + 1];
        float a0 = bl, a1 = 0.f, a2 = 0.f, a3 = 0.f;
        for (; j + 4 <= jend; j += 4) {
            int s0 = srcbuf[j], s1 = srcbuf[j + 1];
            int s2 = srcbuf[j + 2], s3 = srcbuf[j + 3];
            a0 += bf2f(hbf[(size_t)s0 * 64 + lane]);
            a1 += bf2f(hbf[(size_t)s1 * 64 + lane]);
            a2 += bf2f(hbf[(size_t)s2 * 64 + lane]);
            a3 += bf2f(hbf[(size_t)s3 * 64 + lane]);
        }
        for (; j < jend; ++j)
            a0 += bf2f(hbf[(size_t)srcbuf[j] * 64 + lane]);
        out[(size_t)row * 64 + lane] = (a0 + a1) + (a2 + a3);
    }
}

extern "C" void kernel_launch(void* const* d_in, const int* in_sizes, int n_in,
                              void* d_out, int out_size, void* d_ws, size_t ws_size,
                              hipStream_t stream) {
    const float* drug_x = (const float*)d_in[0];
    const float* dis_x  = (const float*)d_in[1];
    const float* W1     = (const float*)d_in[2];
    const float* b1     = (const float*)d_in[3];
    const float* W2     = (const float*)d_in[4];
    const float* b2     = (const float*)d_in[5];
    const int*   ei1    = (const int*)d_in[6];
    const int*   ei2    = (const int*)d_in[7];
    float* out = (float*)d_out;

    // workspace layout (all chunks 16B-aligned)
    char* p = (char*)d_ws;
    __bf16* h1 = (__bf16*)p;   p += (size_t)N_DRUG * NHID * 2;
    __bf16* h2 = (__bf16*)p;   p += (size_t)N_DIS  * NHID * 2;
    int2* bin1 = (int2*)p;     p += (size_t)E_DRUG * 8;
    int2* bin2 = (int2*)p;     p += (size_t)E_DIS  * 8;
    int* bcnt1   = (int*)p;    p += NBKT * 4;
    int* bstart1 = (int*)p;    p += (NBKT + 4) * 4;
    int* bcur1   = (int*)p;    p += NBKT * 4;
    int* bcnt2   = (int*)p;    p += NBKT * 4;
    int* bstart2 = (int*)p;    p += (NBKT + 4) * 4;
    int* bcur2   = (int*)p;    p += NBKT * 4;
    __bf16* Wp1 = (__bf16*)p;  p += (size_t)F_DRUG * NHID * 2;
    __bf16* Wp2 = (__bf16*)p;

    const int SH1 = 7, ROWS1 = 128, B1n = (N_DRUG + ROWS1 - 1) / ROWS1;  // 391
    const int SH2 = 6, ROWS2 = 64,  B2n = (N_DIS  + ROWS2 - 1) / ROWS2;  // 313

    // 1) zero bucket counters
    zero_bcnt_kernel<<<1, 256, 0, stream>>>(bcnt1, bcnt2);
    // 2) bucket histograms
    bucket_hist_kernel<<<1024, 256, 0, stream>>>(ei1, E_DRUG, SH1, bcnt1);
    bucket_hist_kernel<<<640,  256, 0, stream>>>(ei2, E_DIS,  SH2, bcnt2);
    // 3) bucket scans (starts + cursors)
    scan_buckets_kernel<<<2, 64, 0, stream>>>(bcnt1, bstart1, bcur1, bcnt2, bstart2, bcur2);
    // 4) bin edges into bucket runs (coalesced writes)
    bin_kernel<<<(E_DRUG + 4095) / 4096, 256, 0, stream>>>(ei1, E_DRUG, SH1, bcur1, bin1);
    bin_kernel<<<(E_DIS  + 4095) / 4096, 256, 0, stream>>>(ei2, E_DIS,  SH2, bcur2, bin2);
    // 5) prepack W + MFMA GEMMs (h in bf16)
    {
        int n1 = F_DRUG * NHID, n2 = F_DIS * NHID;
        prepack_kernel<<<(n1 + n2 + 255) / 256, 256, 0, stream>>>(W1, Wp1, n1, W2, Wp2, n2);
    }
    mfma_gemm_kernel<F_DRUG><<<(N_DRUG + 127) / 128, 256, 0, stream>>>(drug_x, Wp1, h1, N_DRUG);
    mfma_gemm_kernel<F_DIS ><<<(N_DIS  + 127) / 128, 256, 0, stream>>>(dis_x,  Wp2, h2, N_DIS);
    // 6) fused per-bucket sort + gather (+bias), both graphs in one launch
    sortgather_kernel<<<B1n + B2n, 512, 0, stream>>>(
        bin1, bstart1, (const unsigned short*)h1, b1, out, N_DRUG, B1n, ROWS1,
        bin2, bstart2, (const unsigned short*)h2, b2, out + (size_t)N_DRUG * NHID, N_DIS, ROWS2);
}

// Round 7
// 81.299 us; speedup vs baseline: 12.7354x; 1.9733x over previous
//
#include <hip/hip_runtime.h>

#define N_DRUG 50000
#define F_DRUG 256
#define E_DRUG 1000000
#define N_DIS  20000
#define F_DIS  128
#define E_DIS  640000
#define NHID   64

#define NBKT  512          // padded LDS bucket-hist size in bin (actual 391 / 313)
#define SH1   7
#define ROWS1 128
#define NBB1  391          // ceil(N_DRUG/128)
#define CAPB1 3072         // mean 2560, sd ~51 -> +10 sigma
#define SH2   6
#define ROWS2 64
#define NBB2  313          // ceil(N_DIS/64)
#define CAPB2 2560         // mean 2048, sd ~45 -> +11 sigma

#define BINCH 2048         // edges per bin block
#define NCH1  489          // ceil(E_DRUG/2048)
#define NCH2  313          // ceil(E_DIS/2048)

#define NBG1  391          // ceil(N_DRUG/128) gemm blocks
#define NBG2  157          // ceil(N_DIS/128)

typedef __bf16 bf16x8 __attribute__((ext_vector_type(8)));
typedef float  f32x4  __attribute__((ext_vector_type(4)));

__device__ inline float bfl(unsigned u) {
    union { unsigned i; float f; } c; c.i = u << 16; return c.f;
}
__device__ inline float bfh(unsigned u) {
    union { unsigned i; float f; } c; c.i = u & 0xffff0000u; return c.f;
}

// ---------------- zero bucket cursors ----------------
__global__ void zero_kernel(int* __restrict__ g1, int* __restrict__ g2) {
    for (int i = threadIdx.x; i < NBB1; i += 256) g1[i] = 0;
    for (int i = threadIdx.x; i < NBB2; i += 256) g2[i] = 0;
}

// ---------------- bin edges into fixed-capacity bucket runs (both graphs) ----------------
__global__ void __launch_bounds__(256)
bin_all_kernel(const int* __restrict__ ei1, int* __restrict__ gcur1, int2* __restrict__ bin1,
               const int* __restrict__ ei2, int* __restrict__ gcur2, int2* __restrict__ bin2) {
    __shared__ int hist[NBKT];
    __shared__ int excl[NBKT];
    __shared__ int gbase[NBKT];
    __shared__ int2 buf[BINCH];

    const int* ei; int* gcur; int2* binned; int E, shift, capb, cb;
    if ((int)blockIdx.x < NCH1) {
        ei = ei1; gcur = gcur1; binned = bin1; E = E_DRUG; shift = SH1; capb = CAPB1;
        cb = blockIdx.x;
    } else {
        ei = ei2; gcur = gcur2; binned = bin2; E = E_DIS; shift = SH2; capb = CAPB2;
        cb = blockIdx.x - NCH1;
    }

    const int tid = threadIdx.x;
    const int base = cb * BINCH;
    const int total = min(BINCH, E - base);

    for (int i = tid; i < NBKT; i += 256) hist[i] = 0;
    __syncthreads();

    int2 my[8];
    int mybkt[8];
    int myloc[8];
#pragma unroll
    for (int j = 0; j < 8; ++j) {
        int e = base + j * 256 + tid;
        if (e < E) {
            int s = ei[e];
            int d = ei[E + e];
            my[j] = make_int2(s, d);
            mybkt[j] = d >> shift;
            myloc[j] = atomicAdd(&hist[mybkt[j]], 1);
        } else {
            mybkt[j] = -1;
        }
    }
    __syncthreads();

    if (tid < 64) {
        int run = 0;
        for (int ch = 0; ch < NBKT / 64; ++ch) {
            int v = hist[ch * 64 + tid];
            int incl = v;
#pragma unroll
            for (int off = 1; off < 64; off <<= 1) {
                int t = __shfl_up(incl, off);
                if (tid >= off) incl += t;
            }
            excl[ch * 64 + tid] = run + incl - v;
            run += __shfl(incl, 63);
        }
    }
    __syncthreads();

    for (int i = tid; i < NBKT; i += 256) {
        int c = hist[i];
        if (c) gbase[i] = atomicAdd(&gcur[i], c);
    }
    __syncthreads();

#pragma unroll
    for (int j = 0; j < 8; ++j)
        if (mybkt[j] >= 0) buf[excl[mybkt[j]] + myloc[j]] = my[j];
    __syncthreads();

    for (int s = tid; s < total; s += 256) {
        int2 p = buf[s];
        int b = p.y >> shift;
        int idx = gbase[b] + (s - excl[b]);
        if (idx < capb)                       // overflow guard (statistically unreachable)
            binned[(size_t)b * capb + idx] = p;
    }
}

// ---------------- GEMM (both graphs, one launch): h[M,64](bf16) = bf16(x) @ bf16(W) ----
// W prepacked into LDS fragment layout inline (fp32 -> bf16 on the fly).
__global__ void __launch_bounds__(256)
gemm_all_kernel(const float* __restrict__ x1, const float* __restrict__ W1, __bf16* __restrict__ h1,
                const float* __restrict__ x2, const float* __restrict__ W2, __bf16* __restrict__ h2) {
    __shared__ __bf16 Wlds[256 * 64];

    const float* x; const float* W; __bf16* h; int M, K, lb;
    if ((int)blockIdx.x < NBG1) {
        x = x1; W = W1; h = h1; M = N_DRUG; K = F_DRUG; lb = blockIdx.x;
    } else {
        x = x2; W = W2; h = h2; M = N_DIS; K = F_DIS; lb = blockIdx.x - NBG1;
    }

    for (int idx = threadIdx.x; idx < K * 64; idx += 256) {
        int k = idx >> 6, col = idx & 63;
        Wlds[((k >> 3) * 64 + col) * 8 + (k & 7)] = (__bf16)W[idx];
    }
    __syncthreads();

    const int wid = threadIdx.x >> 6, lane = threadIdx.x & 63;
    const int l15 = lane & 15, lhi = lane >> 4;
    const int r0 = lb * 128 + wid * 32;
    if (r0 >= M) return;

    f32x4 acc[2][4];
#pragma unroll
    for (int m = 0; m < 2; ++m)
#pragma unroll
        for (int c = 0; c < 4; ++c) acc[m][c] = {0.f, 0.f, 0.f, 0.f};

    int rowA0 = r0 + l15;
    int rowA1 = r0 + 16 + l15;
    int cr0 = rowA0 < M ? rowA0 : M - 1;
    int cr1 = rowA1 < M ? rowA1 : M - 1;
    const float* pA0 = x + (size_t)cr0 * K + lhi * 8;
    const float* pA1 = x + (size_t)cr1 * K + lhi * 8;
    const bf16x8* Wv = (const bf16x8*)Wlds;

    for (int kk = 0; kk < K; kk += 32) {
        float4 a0l = *(const float4*)(pA0 + kk);
        float4 a0h = *(const float4*)(pA0 + kk + 4);
        float4 a1l = *(const float4*)(pA1 + kk);
        float4 a1h = *(const float4*)(pA1 + kk + 4);
        bf16x8 af0, af1;
        af0[0] = (__bf16)a0l.x; af0[1] = (__bf16)a0l.y;
        af0[2] = (__bf16)a0l.z; af0[3] = (__bf16)a0l.w;
        af0[4] = (__bf16)a0h.x; af0[5] = (__bf16)a0h.y;
        af0[6] = (__bf16)a0h.z; af0[7] = (__bf16)a0h.w;
        af1[0] = (__bf16)a1l.x; af1[1] = (__bf16)a1l.y;
        af1[2] = (__bf16)a1l.z; af1[3] = (__bf16)a1l.w;
        af1[4] = (__bf16)a1h.x; af1[5] = (__bf16)a1h.y;
        af1[6] = (__bf16)a1h.z; af1[7] = (__bf16)a1h.w;
        const int kblk = (kk >> 3) + lhi;
#pragma unroll
        for (int c = 0; c < 4; ++c) {
            bf16x8 bf = Wv[kblk * 64 + c * 16 + l15];
            acc[0][c] = __builtin_amdgcn_mfma_f32_16x16x32_bf16(af0, bf, acc[0][c], 0, 0, 0);
            acc[1][c] = __builtin_amdgcn_mfma_f32_16x16x32_bf16(af1, bf, acc[1][c], 0, 0, 0);
        }
    }

#pragma unroll
    for (int m = 0; m < 2; ++m) {
        int rbase = r0 + m * 16 + lhi * 4;
#pragma unroll
        for (int c = 0; c < 4; ++c) {
            int col = c * 16 + l15;
#pragma unroll
            for (int r = 0; r < 4; ++r) {
                int row = rbase + r;
                if (row < M) h[(size_t)row * 64 + col] = (__bf16)acc[m][c][r];
            }
        }
    }
}

// ---------------- fused per-bucket sort + 4-edge-per-load gather ----------------
// 512 threads = 8 waves per bucket. LDS CSR (int atomics), then gather where
// lane = (group g = lane>>4) x (feature quad q = lane&15): one wave-load covers 4 edges.
__global__ void __launch_bounds__(512)
sortgather_kernel(const int2* __restrict__ bin1, const int* __restrict__ gc1,
                  const unsigned short* __restrict__ h1, const float* __restrict__ bias1,
                  float* __restrict__ out1,
                  const int2* __restrict__ bin2, const int* __restrict__ gc2,
                  const unsigned short* __restrict__ h2, const float* __restrict__ bias2,
                  float* __restrict__ out2) {
    __shared__ int hist[ROWS1];
    __shared__ int nstart[ROWS1 + 1];
    __shared__ int cur[ROWS1];
    __shared__ int srcbuf[CAPB1];

    const int2* binned; const unsigned short* hbf; const float* bias; float* out;
    int N, b, rows, capb;
    if ((int)blockIdx.x < NBB1) {
        binned = bin1; hbf = h1; bias = bias1; out = out1;
        N = N_DRUG; b = blockIdx.x; rows = ROWS1; capb = CAPB1;
        binned += (size_t)b * CAPB1;
    } else {
        binned = bin2; hbf = h2; bias = bias2; out = out2;
        N = N_DIS; b = blockIdx.x - NBB1; rows = ROWS2; capb = CAPB2;
        binned += (size_t)b * CAPB2;
    }
    const int cnt = min((blockIdx.x < NBB1 ? gc1[b] : gc2[b]), capb);

    const int tid = threadIdx.x;
    const int lane = tid & 63, w = tid >> 6;
    const int mask = rows - 1;

    for (int i = tid; i < rows; i += 512) hist[i] = 0;
    __syncthreads();

    // pass 1: per-node histogram
    for (int i = tid; i < cnt; i += 512)
        atomicAdd(&hist[binned[i].y & mask], 1);
    __syncthreads();

    // exclusive scan by wave 0
    if (tid < 64) {
        int run = 0;
        for (int ch = 0; ch * 64 < rows; ++ch) {
            int v = hist[ch * 64 + tid];
            int incl = v;
#pragma unroll
            for (int off = 1; off < 64; off <<= 1) {
                int t = __shfl_up(incl, off);
                if (tid >= off) incl += t;
            }
            nstart[ch * 64 + tid] = run + incl - v;
            run += __shfl(incl, 63);
        }
        if (tid == 0) nstart[rows] = run;
    }
    __syncthreads();
    for (int i = tid; i < rows; i += 512) cur[i] = nstart[i];
    __syncthreads();

    // pass 2: scatter src ids into node-sorted LDS order
    for (int i = tid; i < cnt; i += 512) {
        int2 p = binned[i];
        int pos = atomicAdd(&cur[p.y & mask], 1);
        srcbuf[pos] = p.x;
    }
    __syncthreads();

    // gather: wave per node; group g handles every 4th edge; lane owns 4 features.
    const int q = lane & 15, g = lane >> 4;
    const float4 bv = *(const float4*)(bias + (q << 2));
    const int rowbase = b * rows;
    for (int n = w; n < rows; n += 8) {
        int row = rowbase + n;
        int j0 = nstart[n], j1 = nstart[n + 1];
        float ax0 = 0.f, ay0 = 0.f, az0 = 0.f, aw0 = 0.f;
        float ax1 = 0.f, ay1 = 0.f, az1 = 0.f, aw1 = 0.f;
        int j = j0 + g;
        for (; j + 4 < j1; j += 8) {
            int s0 = srcbuf[j];
            int s1 = srcbuf[j + 4];
            uint2 u0 = *(const uint2*)(hbf + ((size_t)s0 << 6) + (q << 2));
            uint2 u1 = *(const uint2*)(hbf + ((size_t)s1 << 6) + (q << 2));
            ax0 += bfl(u0.x); ay0 += bfh(u0.x); az0 += bfl(u0.y); aw0 += bfh(u0.y);
            ax1 += bfl(u1.x); ay1 += bfh(u1.x); az1 += bfl(u1.y); aw1 += bfh(u1.y);
        }
        if (j < j1) {
            int s0 = srcbuf[j];
            uint2 u0 = *(const uint2*)(hbf + ((size_t)s0 << 6) + (q << 2));
            ax0 += bfl(u0.x); ay0 += bfh(u0.x); az0 += bfl(u0.y); aw0 += bfh(u0.y);
        }
        float fx = ax0 + ax1, fy = ay0 + ay1, fz = az0 + az1, fw = aw0 + aw1;
        fx += __shfl_xor(fx, 16); fy += __shfl_xor(fy, 16);
        fz += __shfl_xor(fz, 16); fw += __shfl_xor(fw, 16);
        fx += __shfl_xor(fx, 32); fy += __shfl_xor(fy, 32);
        fz += __shfl_xor(fz, 32); fw += __shfl_xor(fw, 32);
        if (g == 0 && row < N) {
            float4 o = make_float4(fx + bv.x, fy + bv.y, fz + bv.z, fw + bv.w);
            *(float4*)(out + (size_t)row * 64 + (q << 2)) = o;
        }
    }
}

extern "C" void kernel_launch(void* const* d_in, const int* in_sizes, int n_in,
                              void* d_out, int out_size, void* d_ws, size_t ws_size,
                              hipStream_t stream) {
    const float* drug_x = (const float*)d_in[0];
    const float* dis_x  = (const float*)d_in[1];
    const float* W1     = (const float*)d_in[2];
    const float* b1     = (const float*)d_in[3];
    const float* W2     = (const float*)d_in[4];
    const float* b2     = (const float*)d_in[5];
    const int*   ei1    = (const int*)d_in[6];
    const int*   ei2    = (const int*)d_in[7];
    float* out = (float*)d_out;

    // workspace layout (16B-aligned chunks), ~25 MB total
    char* p = (char*)d_ws;
    __bf16* h1 = (__bf16*)p;   p += (size_t)N_DRUG * NHID * 2;
    __bf16* h2 = (__bf16*)p;   p += (size_t)N_DIS  * NHID * 2;
    int* gcur1 = (int*)p;      p += ((NBB1 + 3) & ~3) * 4;
    int* gcur2 = (int*)p;      p += ((NBB2 + 3) & ~3) * 4;
    int2* bin1 = (int2*)p;     p += (size_t)NBB1 * CAPB1 * 8;
    int2* bin2 = (int2*)p;     /* p += NBB2 * CAPB2 * 8 */

    // 1) zero bucket cursors
    zero_kernel<<<1, 256, 0, stream>>>(gcur1, gcur2);
    // 2) bin edges into fixed-capacity bucket runs (both graphs)
    bin_all_kernel<<<NCH1 + NCH2, 256, 0, stream>>>(ei1, gcur1, bin1, ei2, gcur2, bin2);
    // 3) GEMMs with inline W prepack (both graphs)
    gemm_all_kernel<<<NBG1 + NBG2, 256, 0, stream>>>(drug_x, W1, h1, dis_x, W2, h2);
    // 4) fused per-bucket sort + gather (+bias), both graphs
    sortgather_kernel<<<NBB1 + NBB2, 512, 0, stream>>>(
        bin1, gcur1, (const unsigned short*)h1, b1, out,
        bin2, gcur2, (const unsigned short*)h2, b2, out + (size_t)N_DRUG * NHID);
}

// Round 8
// 64.995 us; speedup vs baseline: 15.9300x; 1.2509x over previous
//
#include <hip/hip_runtime.h>

#define N_DRUG 50000
#define F_DRUG 256
#define E_DRUG 1000000
#define N_DIS  20000
#define F_DIS  128
#define E_DIS  640000
#define NHID   64

#define NBKT  512          // padded LDS bucket-hist size (actual 391 / 313)
#define SH1   7
#define ROWS1 128
#define NBB1  391          // ceil(N_DRUG/128)
#define CAPB1 3072         // 6*512; mean 2560, +10 sigma
#define SH2   6
#define ROWS2 64
#define NBB2  313          // ceil(N_DIS/64)
#define CAPB2 2560         // 5*512; mean 2048, +11 sigma

#define BINCH 4096         // edges per bin block
#define NCH1  245          // ceil(E_DRUG/4096)
#define NCH2  157          // ceil(E_DIS/4096)

#define NBG1  391          // gemm blocks drug (128 rows each)
#define NBG2  157          // gemm blocks dis

typedef __bf16 bf16x8 __attribute__((ext_vector_type(8)));
typedef float  f32x4  __attribute__((ext_vector_type(4)));

__device__ inline float bfl(unsigned u) {
    union { unsigned i; float f; } c; c.i = u << 16; return c.f;
}
__device__ inline float bfh(unsigned u) {
    union { unsigned i; float f; } c; c.i = u & 0xffff0000u; return c.f;
}

// ---------------- zero bucket cursors ----------------
__global__ void zero_kernel(int* __restrict__ g1, int* __restrict__ g2) {
    for (int i = threadIdx.x; i < NBB1; i += 256) g1[i] = 0;
    for (int i = threadIdx.x; i < NBB2; i += 256) g2[i] = 0;
}

// ---------------- phase 1: bin (blocks [0,402)) + MFMA GEMM (blocks [402,950)) ----------------
// Bin: edges -> fixed-capacity bucket runs, packed (src<<16)|dst (both fit 16 bits).
// GEMM: h[M,64](bf16) = bf16(x) @ bf16(W), W prepacked into LDS fragment layout inline.
__global__ void __launch_bounds__(256)
phase1_kernel(const int* __restrict__ ei1, int* __restrict__ gcur1, unsigned* __restrict__ bin1,
              const int* __restrict__ ei2, int* __restrict__ gcur2, unsigned* __restrict__ bin2,
              const float* __restrict__ x1, const float* __restrict__ W1, __bf16* __restrict__ h1,
              const float* __restrict__ x2, const float* __restrict__ W2, __bf16* __restrict__ h2) {
    __shared__ int smem[8192];   // 32 KB, role-dependent layout
    const int bid = blockIdx.x;
    const int tid = threadIdx.x;

    if (bid < NCH1 + NCH2) {
        // ---------------- bin role ----------------
        const int* ei; int* gcur; unsigned* binned; int E, shift, capb, cb;
        if (bid < NCH1) {
            ei = ei1; gcur = gcur1; binned = bin1; E = E_DRUG; shift = SH1; capb = CAPB1; cb = bid;
        } else {
            ei = ei2; gcur = gcur2; binned = bin2; E = E_DIS; shift = SH2; capb = CAPB2; cb = bid - NCH1;
        }
        int* hist  = smem;          // 512
        int* excl  = smem + 512;    // 512
        int* gbase = smem + 1024;   // 512
        int* buf   = smem + 1536;   // 4096

        const int base = cb * BINCH;
        const int total = min(BINCH, E - base);

        for (int i = tid; i < NBKT; i += 256) hist[i] = 0;
        __syncthreads();

        unsigned my[16]; int mybkt[16]; int myloc[16];
#pragma unroll
        for (int j = 0; j < 16; ++j) {
            int e = base + j * 256 + tid;
            if (e < E) {
                int s = ei[e];
                int d = ei[E + e];
                my[j] = ((unsigned)s << 16) | (unsigned)d;
                mybkt[j] = d >> shift;
                myloc[j] = atomicAdd(&hist[mybkt[j]], 1);
            } else {
                mybkt[j] = -1;
            }
        }
        __syncthreads();

        if (tid < 64) {
            int run = 0;
            for (int ch = 0; ch < NBKT / 64; ++ch) {
                int v = hist[ch * 64 + tid];
                int incl = v;
#pragma unroll
                for (int off = 1; off < 64; off <<= 1) {
                    int t = __shfl_up(incl, off);
                    if (tid >= off) incl += t;
                }
                excl[ch * 64 + tid] = run + incl - v;
                run += __shfl(incl, 63);
            }
        }
        __syncthreads();

        for (int i = tid; i < NBKT; i += 256) {
            int c = hist[i];
            if (c) gbase[i] = atomicAdd(&gcur[i], c);
        }
        __syncthreads();

#pragma unroll
        for (int j = 0; j < 16; ++j)
            if (mybkt[j] >= 0) buf[excl[mybkt[j]] + myloc[j]] = (int)my[j];
        __syncthreads();

        for (int s = tid; s < total; s += 256) {
            unsigned p = (unsigned)buf[s];
            int b = (int)(p & 0xFFFFu) >> shift;
            int idx = gbase[b] + (s - excl[b]);
            if (idx < capb)                       // overflow guard (statistically unreachable)
                binned[(size_t)b * capb + idx] = p;
        }
    } else {
        // ---------------- gemm role ----------------
        __bf16* Wlds = (__bf16*)smem;             // 256*64 bf16 = 32 KB max
        const float* x; const float* W; __bf16* h; int M, K, lb;
        int gb = bid - (NCH1 + NCH2);
        if (gb < NBG1) {
            x = x1; W = W1; h = h1; M = N_DRUG; K = F_DRUG; lb = gb;
        } else {
            x = x2; W = W2; h = h2; M = N_DIS; K = F_DIS; lb = gb - NBG1;
        }

        for (int idx = tid; idx < K * 64; idx += 256) {
            int k = idx >> 6, col = idx & 63;
            Wlds[((k >> 3) * 64 + col) * 8 + (k & 7)] = (__bf16)W[idx];
        }
        __syncthreads();

        const int wid = tid >> 6, lane = tid & 63;
        const int l15 = lane & 15, lhi = lane >> 4;
        const int r0 = lb * 128 + wid * 32;
        if (r0 >= M) return;

        f32x4 acc[2][4];
#pragma unroll
        for (int m = 0; m < 2; ++m)
#pragma unroll
            for (int c = 0; c < 4; ++c) acc[m][c] = {0.f, 0.f, 0.f, 0.f};

        int rowA0 = r0 + l15;
        int rowA1 = r0 + 16 + l15;
        int cr0 = rowA0 < M ? rowA0 : M - 1;
        int cr1 = rowA1 < M ? rowA1 : M - 1;
        const float* pA0 = x + (size_t)cr0 * K + lhi * 8;
        const float* pA1 = x + (size_t)cr1 * K + lhi * 8;
        const bf16x8* Wv = (const bf16x8*)Wlds;

        for (int kk = 0; kk < K; kk += 32) {
            float4 a0l = *(const float4*)(pA0 + kk);
            float4 a0h = *(const float4*)(pA0 + kk + 4);
            float4 a1l = *(const float4*)(pA1 + kk);
            float4 a1h = *(const float4*)(pA1 + kk + 4);
            bf16x8 af0, af1;
            af0[0] = (__bf16)a0l.x; af0[1] = (__bf16)a0l.y;
            af0[2] = (__bf16)a0l.z; af0[3] = (__bf16)a0l.w;
            af0[4] = (__bf16)a0h.x; af0[5] = (__bf16)a0h.y;
            af0[6] = (__bf16)a0h.z; af0[7] = (__bf16)a0h.w;
            af1[0] = (__bf16)a1l.x; af1[1] = (__bf16)a1l.y;
            af1[2] = (__bf16)a1l.z; af1[3] = (__bf16)a1l.w;
            af1[4] = (__bf16)a1h.x; af1[5] = (__bf16)a1h.y;
            af1[6] = (__bf16)a1h.z; af1[7] = (__bf16)a1h.w;
            const int kblk = (kk >> 3) + lhi;
#pragma unroll
            for (int c = 0; c < 4; ++c) {
                bf16x8 bf = Wv[kblk * 64 + c * 16 + l15];
                acc[0][c] = __builtin_amdgcn_mfma_f32_16x16x32_bf16(af0, bf, acc[0][c], 0, 0, 0);
                acc[1][c] = __builtin_amdgcn_mfma_f32_16x16x32_bf16(af1, bf, acc[1][c], 0, 0, 0);
            }
        }

#pragma unroll
        for (int m = 0; m < 2; ++m) {
            int rbase = r0 + m * 16 + lhi * 4;
#pragma unroll
            for (int c = 0; c < 4; ++c) {
                int col = c * 16 + l15;
#pragma unroll
                for (int r = 0; r < 4; ++r) {
                    int row = rbase + r;
                    if (row < M) h[(size_t)row * 64 + col] = (__bf16)acc[m][c][r];
                }
            }
        }
    }
}

// ---------------- phase 2: fused per-bucket sort + 4-edge-per-load gather ----------------
// 512 threads = 8 waves per bucket. Packed bins read ONCE into 6 regs/thread
// (compile-time indices), LDS CSR via int atomics, then wave-per-node gather.
__global__ void __launch_bounds__(512)
sortgather_kernel(const unsigned* __restrict__ bin1, const int* __restrict__ gc1,
                  const unsigned short* __restrict__ h1, const float* __restrict__ bias1,
                  float* __restrict__ out1,
                  const unsigned* __restrict__ bin2, const int* __restrict__ gc2,
                  const unsigned short* __restrict__ h2, const float* __restrict__ bias2,
                  float* __restrict__ out2) {
    __shared__ int hist[ROWS1];
    __shared__ int nstart[ROWS1 + 1];
    __shared__ int cur[ROWS1];
    __shared__ int srcbuf[CAPB1];

    const unsigned* pb; const unsigned short* hbf; const float* bias; float* out;
    int N, b, rows, capb, cnt;
    if ((int)blockIdx.x < NBB1) {
        b = blockIdx.x;
        pb = bin1 + (size_t)b * CAPB1; hbf = h1; bias = bias1; out = out1;
        N = N_DRUG; rows = ROWS1; capb = CAPB1;
        cnt = gc1[b];
    } else {
        b = blockIdx.x - NBB1;
        pb = bin2 + (size_t)b * CAPB2; hbf = h2; bias = bias2; out = out2;
        N = N_DIS; rows = ROWS2; capb = CAPB2;
        cnt = gc2[b];
    }
    cnt = min(cnt, capb);

    const int tid = threadIdx.x;
    const int lane = tid & 63, w = tid >> 6;
    const int mask = rows - 1;

    for (int i = tid; i < rows; i += 512) hist[i] = 0;
    __syncthreads();

    // single global read of the bucket run into registers
    unsigned pv[6];
#pragma unroll
    for (int j = 0; j < 6; ++j) {
        int i = j * 512 + tid;
        pv[j] = (i < cnt) ? pb[i] : 0xFFFFFFFFu;
    }

    // pass 1: per-node histogram
#pragma unroll
    for (int j = 0; j < 6; ++j)
        if (pv[j] != 0xFFFFFFFFu) atomicAdd(&hist[(int)(pv[j] & (unsigned)mask)], 1);
    __syncthreads();

    // exclusive scan by wave 0
    if (tid < 64) {
        int run = 0;
        for (int ch = 0; ch * 64 < rows; ++ch) {
            int v = hist[ch * 64 + tid];
            int incl = v;
#pragma unroll
            for (int off = 1; off < 64; off <<= 1) {
                int t = __shfl_up(incl, off);
                if (tid >= off) incl += t;
            }
            nstart[ch * 64 + tid] = run + incl - v;
            run += __shfl(incl, 63);
        }
        if (tid == 0) nstart[rows] = run;
    }
    __syncthreads();
    for (int i = tid; i < rows; i += 512) cur[i] = nstart[i];
    __syncthreads();

    // pass 2: scatter src ids into node-sorted LDS order
#pragma unroll
    for (int j = 0; j < 6; ++j)
        if (pv[j] != 0xFFFFFFFFu) {
            int pos = atomicAdd(&cur[(int)(pv[j] & (unsigned)mask)], 1);
            srcbuf[pos] = (int)(pv[j] >> 16);
        }
    __syncthreads();

    // gather: wave per node; group g handles every 4th edge; lane owns 4 features.
    const int q = lane & 15, g = lane >> 4;
    const float4 bv = *(const float4*)(bias + (q << 2));
    const int rowbase = b * rows;
    for (int n = w; n < rows; n += 8) {
        int row = rowbase + n;
        int j0 = nstart[n], j1 = nstart[n + 1];
        float ax0 = 0.f, ay0 = 0.f, az0 = 0.f, aw0 = 0.f;
        float ax1 = 0.f, ay1 = 0.f, az1 = 0.f, aw1 = 0.f;
        int j = j0 + g;
        for (; j + 4 < j1; j += 8) {
            int s0 = srcbuf[j];
            int s1 = srcbuf[j + 4];
            uint2 u0 = *(const uint2*)(hbf + ((size_t)s0 << 6) + (q << 2));
            uint2 u1 = *(const uint2*)(hbf + ((size_t)s1 << 6) + (q << 2));
            ax0 += bfl(u0.x); ay0 += bfh(u0.x); az0 += bfl(u0.y); aw0 += bfh(u0.y);
            ax1 += bfl(u1.x); ay1 += bfh(u1.x); az1 += bfl(u1.y); aw1 += bfh(u1.y);
        }
        if (j < j1) {
            int s0 = srcbuf[j];
            uint2 u0 = *(const uint2*)(hbf + ((size_t)s0 << 6) + (q << 2));
            ax0 += bfl(u0.x); ay0 += bfh(u0.x); az0 += bfl(u0.y); aw0 += bfh(u0.y);
        }
        float fx = ax0 + ax1, fy = ay0 + ay1, fz = az0 + az1, fw = aw0 + aw1;
        fx += __shfl_xor(fx, 16); fy += __shfl_xor(fy, 16);
        fz += __shfl_xor(fz, 16); fw += __shfl_xor(fw, 16);
        fx += __shfl_xor(fx, 32); fy += __shfl_xor(fy, 32);
        fz += __shfl_xor(fz, 32); fw += __shfl_xor(fw, 32);
        if (g == 0 && row < N) {
            float4 o = make_float4(fx + bv.x, fy + bv.y, fz + bv.z, fw + bv.w);
            *(float4*)(out + (size_t)row * 64 + (q << 2)) = o;
        }
    }
}

extern "C" void kernel_launch(void* const* d_in, const int* in_sizes, int n_in,
                              void* d_out, int out_size, void* d_ws, size_t ws_size,
                              hipStream_t stream) {
    const float* drug_x = (const float*)d_in[0];
    const float* dis_x  = (const float*)d_in[1];
    const float* W1     = (const float*)d_in[2];
    const float* b1     = (const float*)d_in[3];
    const float* W2     = (const float*)d_in[4];
    const float* b2     = (const float*)d_in[5];
    const int*   ei1    = (const int*)d_in[6];
    const int*   ei2    = (const int*)d_in[7];
    float* out = (float*)d_out;

    // workspace layout (16B-aligned chunks), ~17 MB total
    char* p = (char*)d_ws;
    __bf16* h1 = (__bf16*)p;    p += (size_t)N_DRUG * NHID * 2;
    __bf16* h2 = (__bf16*)p;    p += (size_t)N_DIS  * NHID * 2;
    int* gcur1 = (int*)p;       p += ((NBB1 + 3) & ~3) * 4;
    int* gcur2 = (int*)p;       p += ((NBB2 + 3) & ~3) * 4;
    unsigned* bin1 = (unsigned*)p;  p += (size_t)NBB1 * CAPB1 * 4;
    unsigned* bin2 = (unsigned*)p;  /* p += NBB2 * CAPB2 * 4 */

    // 1) zero bucket cursors
    zero_kernel<<<1, 256, 0, stream>>>(gcur1, gcur2);
    // 2) fused bin + GEMM (independent work, concurrent block roles)
    phase1_kernel<<<NCH1 + NCH2 + NBG1 + NBG2, 256, 0, stream>>>(
        ei1, gcur1, bin1, ei2, gcur2, bin2,
        drug_x, W1, h1, dis_x, W2, h2);
    // 3) fused per-bucket sort + gather (+bias), both graphs
    sortgather_kernel<<<NBB1 + NBB2, 512, 0, stream>>>(
        bin1, gcur1, (const unsigned short*)h1, b1, out,
        bin2, gcur2, (const unsigned short*)h2, b2, out + (size_t)N_DRUG * NHID);
}